// Round 4
// baseline (232.458 us; speedup 1.0000x reference)
//
#include <hip/hip_runtime.h>
#include <hip/hip_cooperative_groups.h>
#include <stdint.h>

#define HH 2048
#define WW 2048
#define NPIX (HH*WW)
#define MROW (WW/32)     // 64 mask words per image row
#define TW 128
#define TH 128
#define NBX (WW/TW)      // 16
#define NBY (HH/TH)      // 16
#define NBLK (NBX*NBY)   // 256 blocks == 256 CUs, 1 block/CU

namespace cg = cooperative_groups;

// One fused cooperative kernel: fw+mask -> gridsync -> contour+w (regs) +
// per-block minmax -> gridsync -> redundant global reduce + normalize + write.
// 1024 thr/block, 16 px/thread (4 float4-quads at stride 1024*4).
__global__ __launch_bounds__(1024, 4) void fused_kernel(
    const float* __restrict__ target, const float* __restrict__ dk,
    uint32_t* __restrict__ gmask, float* __restrict__ pmin,
    float* __restrict__ pmax, float* __restrict__ out)
{
    __shared__ uint8_t  nib[4096];          // per-quad combined nibbles
    __shared__ uint32_t maskw[TH + 8][6];   // halo rows x 192 bits
    __shared__ float    inv_d2[40];         // d^2 -> 1/dist
    __shared__ float    smn[16], smx[16], bc[2];

    cg::grid_group grid = cg::this_grid();

    const int t   = threadIdx.x;
    const int bid = blockIdx.x;
    const int gx0 = (bid & (NBX - 1)) * TW;
    const int gy0 = (bid >> 4) * TH;

    // ---------------- Phase 1: fw (regs) + combined bit-mask (global) ----------------
    uint32_t fwpack[4];                     // 16 fw bytes
    const float4* t4 = (const float4*)target;
    #pragma unroll
    for (int k = 0; k < 4; ++k) {
        int Q  = t + k * 1024;              // tile quad id [0,4096)
        int rl = Q >> 5, qx = Q & 31;       // tile row, quad-in-row
        int qidx = (gy0 + rl) * (WW / 4) + (gx0 >> 2) + qx;
        float4 a = t4[qidx];
        float4 b = t4[qidx + (NPIX / 4)];
        float4 c = t4[qidx + 2 * (NPIX / 4)];
        float4 d = t4[qidx + 3 * (NPIX / 4)];
        float4 e = t4[qidx + 4 * (NPIX / 4)];
        uint32_t f0 = (uint32_t)(a.x + b.x + c.x + d.x + e.x);
        uint32_t f1 = (uint32_t)(a.y + b.y + c.y + d.y + e.y);
        uint32_t f2 = (uint32_t)(a.z + b.z + c.z + d.z + e.z);
        uint32_t f3 = (uint32_t)(a.w + b.w + c.w + d.w + e.w);
        fwpack[k] = f0 | (f1 << 8) | (f2 << 16) | (f3 << 24);
        nib[Q] = (uint8_t)((f0 ? 1u : 0u) | (f1 ? 2u : 0u) | (f2 ? 4u : 0u) | (f3 ? 8u : 0u));
    }
    __syncthreads();
    if (t < 512) {                          // pack 8 nibbles -> one mask word
        const uint32_t* nw = (const uint32_t*)nib;
        uint32_t v0 = nw[t * 2], v1 = nw[t * 2 + 1];
        v0 = (v0 | (v0 >> 4)) & 0x00FF00FFu; v0 = (v0 | (v0 >> 8)) & 0xFFFFu;
        v1 = (v1 | (v1 >> 4)) & 0x00FF00FFu; v1 = (v1 | (v1 >> 8)) & 0xFFFFu;
        uint32_t word = v0 | (v1 << 16);
        int rl = t >> 2, wc = t & 3;        // word covers tile pixels [t*32, t*32+32)
        gmask[(gy0 + rl) * MROW + (gx0 >> 5) + wc] = word;
    }
    __threadfence();
    grid.sync();

    // ---------------- Phase 2: contour + w (regs) + per-block minmax ----------------
    if (t < 81) {
        int iy = t / 9, jx = t - iy * 9;
        int dy = iy - 4, dx = jx - 4;
        int d2 = dy * dy + dx * dx;
        if (d2 != 0)
            inv_d2[d2] = 1.0f / (dk[t] / (1.0f + 1e-10f) + 1e-10f);
    }
    const int w0 = gx0 >> 5;
    if (t < (TH + 8) * 6) {                 // 816 halo words
        int hr = t / 6, wc = t - hr * 6;
        int gy = gy0 - 4 + hr; gy = min(max(gy, 0), HH - 1);
        const uint32_t* rowp = gmask + gy * MROW;
        int wi = w0 - 1 + wc;
        uint32_t v;
        if (wi < 0)            v = (rowp[0] & 1u) ? 0xFFFFFFFFu : 0u;        // left clamp
        else if (wi > MROW-1)  v = (rowp[MROW-1] >> 31) ? 0xFFFFFFFFu : 0u;  // right clamp
        else                   v = rowp[wi];
        maskw[hr][wc] = v;
    }
    __syncthreads();

    float wv[16];
    float lmn = __int_as_float(0x7F800000);
    float lmx = 0.0f;
    #pragma unroll
    for (int k = 0; k < 4; ++k) {
        int Q  = t + k * 1024;
        int rl = Q >> 5, qx = Q & 31, xl = qx * 4;
        int pos = xl + 28;                  // bit of (gx-4) within 192-bit halo row
        int wsel = pos >> 5;
        uint32_t sh = (uint32_t)(pos & 31);
        // center bits of the 4 pixels
        uint64_t rowc = (((uint64_t)maskw[rl + 4][wsel + 1]) << 32) | maskw[rl + 4][wsel];
        uint32_t c4 = ((uint32_t)(rowc >> sh) >> 4) & 0xFu;
        uint32_t cm0 = 0u - (c4 & 1u), cm1 = 0u - ((c4 >> 1) & 1u);
        uint32_t cm2 = 0u - ((c4 >> 2) & 1u), cm3 = 0u - ((c4 >> 3) & 1u);
        uint32_t m0 = 999u, m1 = 999u, m2 = 999u, m3 = 999u;
        #pragma unroll
        for (int dy = 0; dy < 9; ++dy) {
            uint64_t rr = (((uint64_t)maskw[rl + dy][wsel + 1]) << 32) | maskw[rl + dy][wsel];
            uint32_t w12 = (uint32_t)(rr >> sh) & 0xFFFu;
            uint32_t dd = (uint32_t)((dy - 4) * (dy - 4));
            {   uint32_t x = (w12 ^ cm0) & 0x1FFu;
                uint32_t rev = __builtin_bitreverse32(x) >> 23;
                uint32_t g = (((x | rev) >> 4) & 0x1Fu) | 0x100u;
                uint32_t mk = (uint32_t)__builtin_ctz(g);
                m0 = min(m0, mk * mk + dd); }
            {   uint32_t x = ((w12 >> 1) ^ cm1) & 0x1FFu;
                uint32_t rev = __builtin_bitreverse32(x) >> 23;
                uint32_t g = (((x | rev) >> 4) & 0x1Fu) | 0x100u;
                uint32_t mk = (uint32_t)__builtin_ctz(g);
                m1 = min(m1, mk * mk + dd); }
            {   uint32_t x = ((w12 >> 2) ^ cm2) & 0x1FFu;
                uint32_t rev = __builtin_bitreverse32(x) >> 23;
                uint32_t g = (((x | rev) >> 4) & 0x1Fu) | 0x100u;
                uint32_t mk = (uint32_t)__builtin_ctz(g);
                m2 = min(m2, mk * mk + dd); }
            {   uint32_t x = ((w12 >> 3) ^ cm3) & 0x1FFu;
                uint32_t rev = __builtin_bitreverse32(x) >> 23;
                uint32_t g = (((x | rev) >> 4) & 0x1Fu) | 0x100u;
                uint32_t mk = (uint32_t)__builtin_ctz(g);
                m3 = min(m3, mk * mk + dd); }
        }
        uint32_t mj[4] = {m0, m1, m2, m3};
        #pragma unroll
        for (int j = 0; j < 4; ++j) {
            float contour = (mj[j] <= 32u) ? inv_d2[mj[j]] : 0.0f;
            float fwf = (float)((fwpack[k] >> (8 * j)) & 0xFFu);
            float w = fwf + contour;
            w = w * w;
            wv[k * 4 + j] = w;
            lmn = fminf(lmn, w);
            lmx = fmaxf(lmx, w);
        }
    }

    // block reduce -> one partial pair per block (no atomics)
    #pragma unroll
    for (int off = 32; off > 0; off >>= 1) {
        lmn = fminf(lmn, __shfl_xor(lmn, off));
        lmx = fmaxf(lmx, __shfl_xor(lmx, off));
    }
    if ((t & 63) == 0) { smn[t >> 6] = lmn; smx[t >> 6] = lmx; }
    __syncthreads();
    if (t == 0) {
        float mn = smn[0], mx = smx[0];
        #pragma unroll
        for (int i = 1; i < 16; ++i) { mn = fminf(mn, smn[i]); mx = fmaxf(mx, smx[i]); }
        pmin[bid] = mn;
        pmax[bid] = mx;
    }
    __threadfence();
    grid.sync();

    // ---------------- Phase 3: redundant reduce + normalize + write ----------------
    if (t < 256) {
        float mn = pmin[t], mx = pmax[t];
        #pragma unroll
        for (int off = 32; off > 0; off >>= 1) {
            mn = fminf(mn, __shfl_xor(mn, off));
            mx = fmaxf(mx, __shfl_xor(mx, off));
        }
        if ((t & 63) == 0) { smn[t >> 6] = mn; smx[t >> 6] = mx; }
    }
    __syncthreads();
    if (t == 0) {
        bc[0] = fminf(fminf(smn[0], smn[1]), fminf(smn[2], smn[3]));
        bc[1] = fmaxf(fmaxf(smx[0], smx[1]), fmaxf(smx[2], smx[3]));
    }
    __syncthreads();
    const float mn = bc[0];
    const float rden = 1.0f / (bc[1] - mn + 1e-10f);
    #pragma unroll
    for (int k = 0; k < 4; ++k) {
        int Q  = t + k * 1024;
        int rl = Q >> 5, qx = Q & 31;
        float4 o;
        o.x = ((fwpack[k]      ) & 0xFFu) ? (wv[k*4+0] - mn) * rden : 0.0f;
        o.y = ((fwpack[k] >>  8) & 0xFFu) ? (wv[k*4+1] - mn) * rden : 0.0f;
        o.z = ((fwpack[k] >> 16) & 0xFFu) ? (wv[k*4+2] - mn) * rden : 0.0f;
        o.w = ((fwpack[k] >> 24) & 0xFFu) ? (wv[k*4+3] - mn) * rden : 0.0f;
        ((float4*)out)[(gy0 + rl) * (WW / 4) + (gx0 >> 2) + qx] = o;
    }
}

extern "C" void kernel_launch(void* const* d_in, const int* in_sizes, int n_in,
                              void* d_out, int out_size, void* d_ws, size_t ws_size,
                              hipStream_t stream)
{
    const float* target = (const float*)d_in[0];
    const float* dk     = (const float*)d_in[1];
    float* out = (float*)d_out;

    uint8_t* wsb = (uint8_t*)d_ws;
    uint32_t* gmask = (uint32_t*)wsb;                 // 512 KB packed combined-mask
    float*    pmin  = (float*)(wsb + NPIX / 8);       // 1 KB partial mins
    float*    pmax  = pmin + NBLK;                    // 1 KB partial maxs

    void* args[] = { (void*)&target, (void*)&dk, (void*)&gmask,
                     (void*)&pmin, (void*)&pmax, (void*)&out };
    hipLaunchCooperativeKernel((void*)fused_kernel, dim3(NBLK), dim3(1024),
                               args, 0, stream);
}

// Round 5
// 39.430 us; speedup vs baseline: 5.8954x; 5.8954x over previous
//
#include <hip/hip_runtime.h>
#include <hip/hip_fp16.h>
#include <stdint.h>

#define HH 2048
#define WW 2048
#define NPIX (HH*WW)
#define MROW (WW/32)      // 64 mask words per row
#define TSX 64
#define TSY 32
#define NBLK ((WW/TSX)*(HH/TSY))   // 2048 contour blocks

// ---------------- Kernel A: fw u8 plane + bit-packed mask ----------------
__global__ __launch_bounds__(256) void fw_kernel(
    const float* __restrict__ target, uint8_t* __restrict__ fw,
    uint32_t* __restrict__ mask)
{
    __shared__ uint8_t nib[256];
    const int t = threadIdx.x;
    const int i = blockIdx.x * 256 + t;   // quad index, grid sized exactly
    const float4* t4 = (const float4*)target;
    float4 a = t4[i];
    float4 b = t4[(NPIX/4) + i];
    float4 c = t4[2*(NPIX/4) + i];
    float4 d = t4[3*(NPIX/4) + i];
    float4 e = t4[4*(NPIX/4) + i];
    uchar4 o;
    o.x = (unsigned char)(a.x + b.x + c.x + d.x + e.x);
    o.y = (unsigned char)(a.y + b.y + c.y + d.y + e.y);
    o.z = (unsigned char)(a.z + b.z + c.z + d.z + e.z);
    o.w = (unsigned char)(a.w + b.w + c.w + d.w + e.w);
    ((uchar4*)fw)[i] = o;
    nib[t] = (uint8_t)((o.x ? 1u : 0u) | (o.y ? 2u : 0u) | (o.z ? 4u : 0u) | (o.w ? 8u : 0u));
    __syncthreads();
    if (t < 32) {
        const uint8_t* p = nib + t * 8;
        uint32_t w = 0;
        #pragma unroll
        for (int k = 0; k < 8; ++k) w |= (uint32_t)p[k] << (4 * k);
        mask[blockIdx.x * 32 + t] = w;   // 1024 consecutive pixels per block = 32 words
    }
}

// ---------------- Kernel B: contour + w=(fw+contour)^2 -> fp16, per-block min/max ----------------
// 64x32 tile per block, 256 threads (4 waves x 8 rows). Packed halo mask from global.
__global__ __launch_bounds__(256) void contour_kernel(
    const uint8_t* __restrict__ fw, const uint32_t* __restrict__ mask,
    const float* __restrict__ dk,
    __half* __restrict__ wh, float* __restrict__ pmin, float* __restrict__ pmax)
{
    __shared__ uint32_t maskw[TSY + 8][4];  // halo rows x 128 bits (covers gx0-32 .. gx0+95)
    __shared__ float inv_d2[40];            // d^2 -> 1/dist
    __shared__ float redmn[4], redmx[4];

    const int t   = threadIdx.x;
    const int gx0 = blockIdx.x * TSX;
    const int gy0 = blockIdx.y * TSY;

    if (t < 81) {
        int iy = t / 9, jx = t - (t / 9) * 9;
        int dy = iy - 4, dx = jx - 4;
        int d2 = dy * dy + dx * dx;
        if (d2 != 0)
            inv_d2[d2] = 1.0f / (dk[t] / (1.0f + 1e-10f) + 1e-10f);
    }

    // halo mask: word wc covers bits gx0-32+32*wc; rows gy0-4 .. gy0+TSY+3 (clamped)
    const int w0 = gx0 >> 5;
    if (t < (TSY + 8) * 4) {                 // 160 <= 256: one word per thread
        int hr = t >> 2, wc = t & 3;
        int gy = gy0 - 4 + hr; gy = min(max(gy, 0), HH - 1);
        const uint32_t* rowp = mask + gy * MROW;
        int wi = w0 - 1 + wc;
        uint32_t v;
        if (wi < 0)            v = (rowp[0] & 1u) ? 0xFFFFFFFFu : 0u;          // left edge clamp
        else if (wi > MROW-1)  v = (rowp[MROW-1] >> 31) ? 0xFFFFFFFFu : 0u;    // right edge clamp
        else                   v = rowp[wi];
        maskw[hr][wc] = v;
    }
    __syncthreads();

    const int tx   = t & 63;       // tile column
    const int wid  = t >> 6;       // wave id: rows wid*8 .. wid*8+7
    const int r0   = wid * 8;
    const int pos  = tx + 28;      // bit position of gx-4 within the 128-bit row
    const int wsel = pos >> 5;
    const uint32_t sh = (uint32_t)(pos & 31);
    const int gx = gx0 + tx;

    // prefetch the 8 fw bytes (independent loads, overlap latency)
    float fwv[8];
    #pragma unroll
    for (int r = 0; r < 8; ++r)
        fwv[r] = (float)fw[(gy0 + r0 + r) * WW + gx];

    // rolling 9-row window of 9-bit mask slices (bit k = dx offset k-4)
    uint32_t w9[9];
    #pragma unroll
    for (int k = 0; k < 9; ++k) {
        uint32_t lo = maskw[r0 + k][wsel];
        uint32_t hi = maskw[r0 + k][wsel + 1];
        w9[k] = (uint32_t)(((((uint64_t)hi) << 32) | lo) >> sh) & 0x1FFu;
    }

    float lmn = __int_as_float(0x7F800000);  // +inf
    float lmx = 0.0f;

    #pragma unroll
    for (int r = 0; r < 8; ++r) {
        uint32_t cbit = (w9[4] >> 4) & 1u;
        uint32_t cm = 0u - cbit;
        uint32_t mind2 = 999u;
        #pragma unroll
        for (int dy = 0; dy < 9; ++dy) {
            uint32_t x = (w9[dy] ^ cm) & 0x1FFu;              // differ bits
            uint32_t rev = __builtin_bitreverse32(x) >> 23;   // 9-bit reverse: dx -> -dx
            uint32_t g = (((x | rev) >> 4) & 0x1Fu) | 0x100u; // bit k = |dx|==k; sentinel
            uint32_t mk = (uint32_t)__builtin_ctz(g);
            uint32_t d2 = mk * mk + (uint32_t)((dy - 4) * (dy - 4));
            mind2 = min(mind2, d2);
        }
        float contour = (mind2 <= 32u) ? inv_d2[mind2] : 0.0f;
        float wv = fwv[r] + contour;
        wv = wv * wv;
        // store as fp16 (halves the B->C round trip); min/max on the ROUNDED
        // value so C's normalization of fp16 data is consistent
        __half h = __float2half(wv);
        wh[(gy0 + r0 + r) * WW + gx] = h;
        float wr = __half2float(h);
        lmn = fminf(lmn, wr);
        lmx = fmaxf(lmx, wr);
        if (r < 7) {
            #pragma unroll
            for (int k = 0; k < 8; ++k) w9[k] = w9[k + 1];
            uint32_t lo = maskw[r0 + r + 9][wsel];
            uint32_t hi = maskw[r0 + r + 9][wsel + 1];
            w9[8] = (uint32_t)(((((uint64_t)hi) << 32) | lo) >> sh) & 0x1FFu;
        }
    }

    // wave reduce min/max, LDS reduce across 4 waves, one plain store pair per
    // block (same-address atomics were the round-2 disaster: ~190us serialization)
    #pragma unroll
    for (int off = 32; off > 0; off >>= 1) {
        lmn = fminf(lmn, __shfl_xor(lmn, off));
        lmx = fmaxf(lmx, __shfl_xor(lmx, off));
    }
    if (tx == 0) { redmn[wid] = lmn; redmx[wid] = lmx; }
    __syncthreads();
    if (t == 0) {
        float mn = fminf(fminf(redmn[0], redmn[1]), fminf(redmn[2], redmn[3]));
        float mx = fmaxf(fmaxf(redmx[0], redmx[1]), fmaxf(redmx[2], redmx[3]));
        int bid = blockIdx.y * gridDim.x + blockIdx.x;
        pmin[bid] = mn;
        pmax[bid] = mx;
    }
}

// ---------------- Kernel C: redundant partial-reduce + normalize + mask ----------------
// 2048 blocks x 256 threads, 8 px/thread. Each block redundantly reduces the
// 2048 partials (16 KB, L2-hot after B; inter-kernel coherence — no atomics).
__global__ __launch_bounds__(256) void norm_kernel(
    const __half* __restrict__ wh, const uint32_t* __restrict__ mask,
    const float* __restrict__ pmin, const float* __restrict__ pmax,
    float* __restrict__ out)
{
    __shared__ float smn[4], smx[4];
    const int t = threadIdx.x;

    // prologue: reduce 2048 partial pairs
    const float4* pn4 = (const float4*)pmin;
    const float4* px4 = (const float4*)pmax;
    float4 a = pn4[t * 2], b = pn4[t * 2 + 1];
    float4 c = px4[t * 2], d = px4[t * 2 + 1];
    float mn = fminf(fminf(fminf(a.x, a.y), fminf(a.z, a.w)),
                     fminf(fminf(b.x, b.y), fminf(b.z, b.w)));
    float mx = fmaxf(fmaxf(fmaxf(c.x, c.y), fmaxf(c.z, c.w)),
                     fmaxf(fmaxf(d.x, d.y), fmaxf(d.z, d.w)));
    #pragma unroll
    for (int off = 32; off > 0; off >>= 1) {
        mn = fminf(mn, __shfl_xor(mn, off));
        mx = fmaxf(mx, __shfl_xor(mx, off));
    }
    if ((t & 63) == 0) { smn[t >> 6] = mn; smx[t >> 6] = mx; }
    __syncthreads();
    mn = fminf(fminf(smn[0], smn[1]), fminf(smn[2], smn[3]));
    mx = fmaxf(fmaxf(smx[0], smx[1]), fmaxf(smx[2], smx[3]));
    const float rden = 1.0f / (mx - mn + 1e-10f);

    // 8 pixels per thread
    const int i = blockIdx.x * 256 + t;           // 8-px group id
    float4 v = ((const float4*)wh)[i];            // 8 halves
    const __half2* hp = (const __half2*)&v;
    uint32_t mb = (mask[i >> 2] >> ((i & 3) * 8)) & 0xFFu;  // 8 combined bits
    float2 f0 = __half22float2(hp[0]);
    float2 f1 = __half22float2(hp[1]);
    float2 f2 = __half22float2(hp[2]);
    float2 f3 = __half22float2(hp[3]);
    float4 o0, o1;
    o0.x = (mb &   1u) ? (f0.x - mn) * rden : 0.0f;
    o0.y = (mb &   2u) ? (f0.y - mn) * rden : 0.0f;
    o0.z = (mb &   4u) ? (f1.x - mn) * rden : 0.0f;
    o0.w = (mb &   8u) ? (f1.y - mn) * rden : 0.0f;
    o1.x = (mb &  16u) ? (f2.x - mn) * rden : 0.0f;
    o1.y = (mb &  32u) ? (f2.y - mn) * rden : 0.0f;
    o1.z = (mb &  64u) ? (f3.x - mn) * rden : 0.0f;
    o1.w = (mb & 128u) ? (f3.y - mn) * rden : 0.0f;
    ((float4*)out)[i * 2]     = o0;
    ((float4*)out)[i * 2 + 1] = o1;
}

extern "C" void kernel_launch(void* const* d_in, const int* in_sizes, int n_in,
                              void* d_out, int out_size, void* d_ws, size_t ws_size,
                              hipStream_t stream)
{
    const float* target = (const float*)d_in[0];
    const float* dk     = (const float*)d_in[1];
    float* out = (float*)d_out;

    uint8_t* wsb = (uint8_t*)d_ws;
    uint8_t*  fw   = wsb;                                      // 4 MB u8 plane
    uint32_t* mask = (uint32_t*)(wsb + NPIX);                  // 512 KB packed mask
    __half*   wh   = (__half*)(wsb + NPIX + NPIX/8);           // 8 MB fp16 w plane
    float*    pmin = (float*)(wsb + NPIX + NPIX/8 + 2*NPIX);   // 8 KB partial mins
    float*    pmax = pmin + NBLK;                              // 8 KB partial maxs

    fw_kernel<<<NPIX / 4 / 256, 256, 0, stream>>>(target, fw, mask);

    dim3 gridB(WW / TSX, HH / TSY);
    contour_kernel<<<gridB, 256, 0, stream>>>(fw, mask, dk, wh, pmin, pmax);

    norm_kernel<<<NPIX / 8 / 256, 256, 0, stream>>>(wh, mask, pmin, pmax, out);
}

// Round 6
// 35.085 us; speedup vs baseline: 6.6255x; 1.1238x over previous
//
#include <hip/hip_runtime.h>
#include <stdint.h>

#define HH 2048
#define WW 2048
#define NPIX (HH*WW)
#define MROW (WW/32)      // 64 mask words per row
#define TSX 64
#define TSY 32
#define NBLK ((WW/TSX)*(HH/TSY))   // 2048 contour blocks

// ---------------- Kernel A: fw u8 plane + bit-packed combined mask ----------------
__global__ __launch_bounds__(256) void fw_kernel(
    const float* __restrict__ target, uint8_t* __restrict__ fw,
    uint32_t* __restrict__ mask)
{
    __shared__ uint8_t nib[256];
    const int t = threadIdx.x;
    const int i = blockIdx.x * 256 + t;   // quad index, grid sized exactly
    const float4* t4 = (const float4*)target;
    float4 a = t4[i];
    float4 b = t4[(NPIX/4) + i];
    float4 c = t4[2*(NPIX/4) + i];
    float4 d = t4[3*(NPIX/4) + i];
    float4 e = t4[4*(NPIX/4) + i];
    uchar4 o;
    o.x = (unsigned char)(a.x + b.x + c.x + d.x + e.x);
    o.y = (unsigned char)(a.y + b.y + c.y + d.y + e.y);
    o.z = (unsigned char)(a.z + b.z + c.z + d.z + e.z);
    o.w = (unsigned char)(a.w + b.w + c.w + d.w + e.w);
    ((uchar4*)fw)[i] = o;
    nib[t] = (uint8_t)((o.x ? 1u : 0u) | (o.y ? 2u : 0u) | (o.z ? 4u : 0u) | (o.w ? 8u : 0u));
    __syncthreads();
    if (t < 32) {
        const uint8_t* p = nib + t * 8;
        uint32_t w = 0;
        #pragma unroll
        for (int k = 0; k < 8; ++k) w |= (uint32_t)p[k] << (4 * k);
        mask[blockIdx.x * 32 + t] = w;   // 1024 consecutive pixels per block = 32 words
    }
}

// ---------------- Kernel B: contour -> byte code, per-block min/max ----------------
// 64x32 tile, 256 threads; thread = (row rl=t>>3, 8-px group xg=t&7).
// Code byte = ((enc-1)<<3)|fw, enc = mind2 (<=32) or 26 ("none"; 26 unachievable).
__global__ __launch_bounds__(256) void contour_kernel(
    const uint8_t* __restrict__ fw, const uint32_t* __restrict__ mask,
    const float* __restrict__ dk,
    uint8_t* __restrict__ wcode, float* __restrict__ pmin, float* __restrict__ pmax)
{
    __shared__ uint32_t maskw[TSY + 8][4];  // halo rows x 128 bits (gx0-32 .. gx0+95)
    __shared__ uint8_t  lutm2[512];         // 9-bit diff-mask -> min|dx|^2 (8->64 sentinel)
    __shared__ float    inv_ext[101];       // d^2 -> 1/dist, 0 where not achievable/none
    __shared__ float    redmn[4], redmx[4];

    const int t   = threadIdx.x;
    const int gx0 = blockIdx.x * TSX;
    const int gy0 = blockIdx.y * TSY;

    // phase 0: zero inv table, build min|dx|^2 LUT, load halo words
    if (t < 101) inv_ext[t] = 0.0f;
    for (int idx = t; idx < 512; idx += 256) {
        uint32_t rev = __builtin_bitreverse32((uint32_t)idx) >> 23;   // dx -> -dx
        uint32_t g = ((((uint32_t)idx | rev) >> 4) & 0x1Fu) | 0x100u;
        uint32_t mk = (uint32_t)__builtin_ctz(g);                     // min|dx| or 8
        lutm2[idx] = (uint8_t)(mk * mk);
    }
    const int w0 = gx0 >> 5;
    if (t < (TSY + 8) * 4) {                 // 160 halo words, one per thread
        int hr = t >> 2, wc = t & 3;
        int gy = gy0 - 4 + hr; gy = min(max(gy, 0), HH - 1);
        const uint32_t* rowp = mask + gy * MROW;
        int wi = w0 - 1 + wc;
        uint32_t v;
        if (wi < 0)            v = (rowp[0] & 1u) ? 0xFFFFFFFFu : 0u;          // left clamp
        else if (wi > MROW-1)  v = (rowp[MROW-1] >> 31) ? 0xFFFFFFFFu : 0u;    // right clamp
        else                   v = rowp[wi];
        maskw[hr][wc] = v;
    }
    __syncthreads();
    // phase 1: fill achievable inverse-distance entries from dk
    if (t < 81) {
        int iy = t / 9, jx = t - (t / 9) * 9;
        int dy = iy - 4, dx = jx - 4;
        int d2 = dy * dy + dx * dx;
        if (d2 != 0)
            inv_ext[d2] = 1.0f / (dk[t] / (1.0f + 1e-10f) + 1e-10f);
    }
    __syncthreads();

    const int rl  = t >> 3;        // tile row 0..31
    const int xg  = t & 7;         // 8-px group in row
    const int gy  = gy0 + rl;
    const int gxb = gx0 + xg * 8;

    // 8 fw bytes for this thread
    uint32_t fwlo = *(const uint32_t*)(fw + gy * WW + gxb);
    uint32_t fwhi = *(const uint32_t*)(fw + gy * WW + gxb + 4);

    // 9 halo-row windows; bit b of wrow = column (gxb - 4 + b); valid bits >= 16
    const int pos  = xg * 8 + 28;
    const int wsel = pos >> 5;
    const uint32_t sh = (uint32_t)(pos & 31);
    uint32_t wrow[9];
    #pragma unroll
    for (int k = 0; k < 9; ++k) {
        uint64_t v = (((uint64_t)maskw[rl + k][wsel + 1]) << 32) | maskw[rl + k][wsel];
        wrow[k] = (uint32_t)(v >> sh);
    }
    // row-pair fold: diff(+k)|diff(-k) = (center ? ~(r+&r-) : (r+|r-)) = sel^cm
    uint32_t orx[4], andx[4];
    #pragma unroll
    for (int k = 1; k <= 4; ++k) {
        orx[k-1]  = wrow[4 - k] | wrow[4 + k];
        andx[k-1] = wrow[4 - k] & wrow[4 + k];
    }

    float lmn = __int_as_float(0x7F800000);
    float lmx = 0.0f;
    uint32_t outb0 = 0, outb1 = 0;

    #pragma unroll
    for (int j = 0; j < 8; ++j) {
        uint32_t craw = (wrow[4] >> (4 + j)) & 1u;
        uint32_t cm = 0u - craw;
        uint32_t x0 = ((wrow[4] ^ cm) >> j) & 0x1FFu;     // dy=0 diff bits (center self-0)
        uint32_t d2m = (uint32_t)lutm2[x0];
        #pragma unroll
        for (int k = 1; k <= 4; ++k) {
            uint32_t sel = craw ? andx[k-1] : orx[k-1];
            uint32_t x = ((sel ^ cm) >> j) & 0x1FFu;
            uint32_t d2 = (uint32_t)lutm2[x] + (uint32_t)(k * k);
            d2m = min(d2m, d2);
        }
        // d2m: achievable value <=32, or 64..80/100 = "none"
        float contour = inv_ext[d2m];                     // 0 for "none"
        uint32_t enc = (d2m > 32u) ? 26u : d2m;
        uint32_t fwj = (j < 4 ? (fwlo >> (8 * j)) : (fwhi >> (8 * (j - 4)))) & 0xFFu;
        uint32_t code = ((enc - 1u) << 3) | fwj;
        if (j < 4) outb0 |= code << (8 * j);
        else       outb1 |= code << (8 * (j - 4));
        float wv = (float)fwj + contour;
        wv = wv * wv;
        lmn = fminf(lmn, wv);
        lmx = fmaxf(lmx, wv);
    }
    uint2 ob; ob.x = outb0; ob.y = outb1;
    *(uint2*)(wcode + gy * WW + gxb) = ob;

    // wave reduce min/max, LDS reduce, one plain store pair per block
    // (same-address atomics were the round-2 disaster: ~190us serialization)
    #pragma unroll
    for (int off = 32; off > 0; off >>= 1) {
        lmn = fminf(lmn, __shfl_xor(lmn, off));
        lmx = fmaxf(lmx, __shfl_xor(lmx, off));
    }
    if ((t & 63) == 0) { redmn[t >> 6] = lmn; redmx[t >> 6] = lmx; }
    __syncthreads();
    if (t == 0) {
        float mn = fminf(fminf(redmn[0], redmn[1]), fminf(redmn[2], redmn[3]));
        float mx = fmaxf(fmaxf(redmx[0], redmx[1]), fmaxf(redmx[2], redmx[3]));
        int bid = blockIdx.y * gridDim.x + blockIdx.x;
        pmin[bid] = mn;
        pmax[bid] = mx;
    }
}

// ---------------- Kernel C: redundant partial-reduce + LUT decode + normalize ----------------
// 2048 blocks x 256 threads, 8 px/thread. w rebuilt bit-exactly from code byte.
__global__ __launch_bounds__(256) void norm_kernel(
    const uint8_t* __restrict__ wcode, const float* __restrict__ dk,
    const float* __restrict__ pmin, const float* __restrict__ pmax,
    float* __restrict__ out)
{
    __shared__ float ct[33];       // d^2 -> 1/dist (0 where none, incl code 26)
    __shared__ float wlut[256];    // code byte -> w value
    __shared__ float smn[4], smx[4];
    const int t = threadIdx.x;

    if (t < 33) ct[t] = 0.0f;
    // load partials while table phases run
    const float4* pn4 = (const float4*)pmin;
    const float4* px4 = (const float4*)pmax;
    float4 a = pn4[t * 2], b = pn4[t * 2 + 1];
    float4 c = px4[t * 2], d = px4[t * 2 + 1];
    __syncthreads();
    if (t < 81) {
        int iy = t / 9, jx = t - (t / 9) * 9;
        int dy = iy - 4, dx = jx - 4;
        int d2 = dy * dy + dx * dx;
        if (d2 != 0) ct[d2] = 1.0f / (dk[t] / (1.0f + 1e-10f) + 1e-10f);
    }
    __syncthreads();
    {   // build decode LUT: identical arithmetic to B -> bit-exact
        float wv = (float)(t & 7) + ct[(t >> 3) + 1];
        wlut[t] = wv * wv;
    }
    float mn = fminf(fminf(fminf(a.x, a.y), fminf(a.z, a.w)),
                     fminf(fminf(b.x, b.y), fminf(b.z, b.w)));
    float mx = fmaxf(fmaxf(fmaxf(c.x, c.y), fmaxf(c.z, c.w)),
                     fmaxf(fmaxf(d.x, d.y), fmaxf(d.z, d.w)));
    #pragma unroll
    for (int off = 32; off > 0; off >>= 1) {
        mn = fminf(mn, __shfl_xor(mn, off));
        mx = fmaxf(mx, __shfl_xor(mx, off));
    }
    if ((t & 63) == 0) { smn[t >> 6] = mn; smx[t >> 6] = mx; }
    __syncthreads();
    mn = fminf(fminf(smn[0], smn[1]), fminf(smn[2], smn[3]));
    mx = fmaxf(fmaxf(smx[0], smx[1]), fmaxf(smx[2], smx[3]));
    const float rden = 1.0f / (mx - mn + 1e-10f);

    const int i = blockIdx.x * 256 + t;          // 8-px group id
    uint2 cb = ((const uint2*)wcode)[i];
    uint32_t b0 = cb.x, b1 = cb.y;
    float4 o0, o1;
    o0.x = (b0 & 7u)         ? (wlut[b0 & 0xFFu] - mn) * rden         : 0.0f;
    o0.y = ((b0 >> 8) & 7u)  ? (wlut[(b0 >> 8) & 0xFFu] - mn) * rden  : 0.0f;
    o0.z = ((b0 >> 16) & 7u) ? (wlut[(b0 >> 16) & 0xFFu] - mn) * rden : 0.0f;
    o0.w = ((b0 >> 24) & 7u) ? (wlut[b0 >> 24] - mn) * rden           : 0.0f;
    o1.x = (b1 & 7u)         ? (wlut[b1 & 0xFFu] - mn) * rden         : 0.0f;
    o1.y = ((b1 >> 8) & 7u)  ? (wlut[(b1 >> 8) & 0xFFu] - mn) * rden  : 0.0f;
    o1.z = ((b1 >> 16) & 7u) ? (wlut[(b1 >> 16) & 0xFFu] - mn) * rden : 0.0f;
    o1.w = ((b1 >> 24) & 7u) ? (wlut[b1 >> 24] - mn) * rden           : 0.0f;
    ((float4*)out)[i * 2]     = o0;
    ((float4*)out)[i * 2 + 1] = o1;
}

extern "C" void kernel_launch(void* const* d_in, const int* in_sizes, int n_in,
                              void* d_out, int out_size, void* d_ws, size_t ws_size,
                              hipStream_t stream)
{
    const float* target = (const float*)d_in[0];
    const float* dk     = (const float*)d_in[1];
    float* out = (float*)d_out;

    uint8_t* wsb = (uint8_t*)d_ws;
    uint8_t*  fw    = wsb;                                   // 4 MB u8 fw plane
    uint8_t*  wcode = wsb + NPIX;                            // 4 MB u8 code plane
    uint32_t* mask  = (uint32_t*)(wsb + 2 * NPIX);           // 512 KB packed mask
    float*    pmin  = (float*)(wsb + 2 * NPIX + NPIX / 8);   // 8 KB partial mins
    float*    pmax  = pmin + NBLK;                           // 8 KB partial maxs

    fw_kernel<<<NPIX / 4 / 256, 256, 0, stream>>>(target, fw, mask);

    dim3 gridB(WW / TSX, HH / TSY);
    contour_kernel<<<gridB, 256, 0, stream>>>(fw, mask, dk, wcode, pmin, pmax);

    norm_kernel<<<NPIX / 8 / 256, 256, 0, stream>>>(wcode, dk, pmin, pmax, out);
}